// Round 1
// baseline (487.023 us; speedup 1.0000x reference)
//
#include <hip/hip_runtime.h>

// ---------------- common ----------------
typedef float  f32x4  __attribute__((ext_vector_type(4)));
typedef short  bf16x8 __attribute__((ext_vector_type(8)));
typedef unsigned short u16;
typedef unsigned int   u32;

#define DI static __device__ __forceinline__

DI u16 f2bf(float f) {                 // RNE float -> bf16 bits
    u32 u = __float_as_uint(f);
    u += 0x7FFFu + ((u >> 16) & 1u);
    return (u16)(u >> 16);
}

// dims
// B=8 N=128 F_IN=64 F_E=16 H=256 L=8

// ---------------- setup kernels ----------------

// h0 = x @ node_W + node_b       grid: 1024 blocks x 256
__global__ void k_h0(const float* __restrict__ x, const float* __restrict__ nW,
                     const float* __restrict__ nb, float* __restrict__ h) {
    __shared__ float xr[64];
    int row = blockIdx.x, c = threadIdx.x;
    if (c < 64) xr[c] = x[row * 64 + c];
    __syncthreads();
    float acc = nb[c];
#pragma unroll
    for (int k = 0; k < 64; ++k) acc += xr[k] * nW[k * 256 + c];
    h[row * 256 + c] = acc;
}

// edge_attr -> bf16 fragment layout, K padded 16->32 with zeros.
// ef[((b*128+i)*8 + nt)*64 + lane][8]   j = nt*16+(lane&15), k0=(lane>>4)*8
// grid: 2048 x 256  (524288 threads, one uint4 each)
__global__ void k_edgefrag(const float* __restrict__ ea, u16* __restrict__ ef) {
    int gid = blockIdx.x * 256 + threadIdx.x;
    int lane = gid & 63, nt = (gid >> 6) & 7, i = (gid >> 9) & 127, b = gid >> 16;
    int j = nt * 16 + (lane & 15), k0 = (lane >> 4) * 8;
    uint4 out = {0u, 0u, 0u, 0u};
    if (k0 < 16) {
        const float* p = ea + (((size_t)(b * 128 + i) * 128 + j) * 16 + k0);
        u16 us[8];
#pragma unroll
        for (int t = 0; t < 8; ++t) us[t] = f2bf(p[t]);
        out.x = (u32)us[0] | ((u32)us[1] << 16);
        out.y = (u32)us[2] | ((u32)us[3] << 16);
        out.z = (u32)us[4] | ((u32)us[5] << 16);
        out.w = (u32)us[6] | ((u32)us[7] << 16);
    }
    ((uint4*)ef)[gid] = out;
}

// Wf1 = edge_W @ W1[l]  packed as A-fragments (M=h, K=16 padded to 32)
// wf[(l*16 + mt)*64 + lane][8]   h = mt*16+(lane&15), k=(lane>>4)*8+i (>=16 -> 0)
// grid: 32 x 256 (8192 threads)
__global__ void k_wf1(const float* __restrict__ eW, const float* __restrict__ W1,
                      u16* __restrict__ wf) {
    int gid = blockIdx.x * 256 + threadIdx.x;
    int lane = gid & 63, mt = (gid >> 6) & 15, l = gid >> 10;
    int hh = mt * 16 + (lane & 15), k0 = (lane >> 4) * 8;
    u16 us[8];
#pragma unroll
    for (int t = 0; t < 8; ++t) {
        int k = k0 + t;
        float acc = 0.f;
        if (k < 16) {
            const float* wrow = eW + k * 256;
            const float* w1c  = W1 + (size_t)l * 65536 + hh;
            for (int c = 0; c < 256; ++c) acc += wrow[c] * w1c[(size_t)c * 256];
            us[t] = f2bf(acc);
        } else us[t] = 0;
    }
    uint4 out;
    out.x = (u32)us[0] | ((u32)us[1] << 16);
    out.y = (u32)us[2] | ((u32)us[3] << 16);
    out.z = (u32)us[4] | ((u32)us[5] << 16);
    out.w = (u32)us[6] | ((u32)us[7] << 16);
    ((uint4*)wf)[gid] = out;
}

// W1^T / W2^T fragment packs: wt[((l*8+kt)*16+mt)*64+lane][8]
//   value = W[l][k][h], h = mt*16+(lane&15), k = kt*32+(lane>>4)*8+i
// grid: 256 x 256 (65536 threads)
__global__ void k_wt(const float* __restrict__ W1, const float* __restrict__ W2,
                     u16* __restrict__ w1t, u16* __restrict__ w2t) {
    int gid = blockIdx.x * 256 + threadIdx.x;
    int lane = gid & 63, mt = (gid >> 6) & 15, kt = (gid >> 10) & 7, l = gid >> 13;
    int hh = mt * 16 + (lane & 15), k = kt * 32 + (lane >> 4) * 8;
    u16 a[8], b[8];
#pragma unroll
    for (int t = 0; t < 8; ++t) {
        size_t idx = (size_t)l * 65536 + (size_t)(k + t) * 256 + hh;
        a[t] = f2bf(W1[idx]);
        b[t] = f2bf(W2[idx]);
    }
    uint4 oa, ob;
    oa.x = (u32)a[0] | ((u32)a[1] << 16); oa.y = (u32)a[2] | ((u32)a[3] << 16);
    oa.z = (u32)a[4] | ((u32)a[5] << 16); oa.w = (u32)a[6] | ((u32)a[7] << 16);
    ob.x = (u32)b[0] | ((u32)b[1] << 16); ob.y = (u32)b[2] | ((u32)b[3] << 16);
    ob.z = (u32)b[4] | ((u32)b[5] << 16); ob.w = (u32)b[6] | ((u32)b[7] << 16);
    ((uint4*)w1t)[gid] = oa;
    ((uint4*)w2t)[gid] = ob;
}

// bias1[l][h] = edge_b @ W1[l] + b1[l]      grid: 8 x 256
__global__ void k_bias1(const float* __restrict__ eb, const float* __restrict__ W1,
                        const float* __restrict__ b1, float* __restrict__ bias1) {
    int gid = blockIdx.x * 256 + threadIdx.x;
    int l = gid >> 8, hh = gid & 255;
    float acc = b1[l * 256 + hh];
    const float* w1c = W1 + (size_t)l * 65536 + hh;
    for (int c = 0; c < 256; ++c) acc += eb[c] * w1c[(size_t)c * 256];
    bias1[gid] = acc;
}

// ---------------- per-layer kernels ----------------

// mask + layernorm -> bf16 rows.   grid: 1024 x 256
__global__ void k_ln(float* __restrict__ h, const int* __restrict__ mask,
                     const float* __restrict__ lng, const float* __restrict__ lnb,
                     u16* __restrict__ hnbf, int l) {
    __shared__ float rs[4], rs2[4];
    int row = blockIdx.x, c = threadIdx.x;
    float mv = (float)mask[row];
    float v = h[row * 256 + c] * mv;
    h[row * 256 + c] = v;          // h := h*m (in place, used by residual later)
    float s = v, s2 = v * v;
    int w = c >> 6, lane = c & 63;
#pragma unroll
    for (int off = 32; off; off >>= 1) {
        s  += __shfl_xor(s,  off);
        s2 += __shfl_xor(s2, off);
    }
    if (lane == 0) { rs[w] = s; rs2[w] = s2; }
    __syncthreads();
    float S  = rs[0] + rs[1] + rs[2] + rs[3];
    float S2 = rs2[0] + rs2[1] + rs2[2] + rs2[3];
    float mu  = S * (1.f / 256.f);
    float var = S2 * (1.f / 256.f) - mu * mu;
    float rstd = rsqrtf(var + 1e-5f);
    float hn = (v - mu) * rstd * lng[l * 256 + c] + lnb[l * 256 + c];
    hnbf[row * 256 + c] = f2bf(hn);
}

// hn1' = h_norm @ W1[l] + bias1[l]  computed transposed (A=W1^T frags, B=hn rows)
// output permuted to match k_msg's GEMM1 D-layout:
//   hn1p[b][((mt*8+nt)*64+lane)*4 + r] = hn1'[j=nt*16+(lane&15)][h=mt*16+(lane>>4)*4+r]
// grid: 32 x 256  (block = (b, quarter of mt))
__global__ __launch_bounds__(256) void k_hn1(const u16* __restrict__ w1t,
        const u16* __restrict__ hnbf, const float* __restrict__ bias1,
        float* __restrict__ hn1p, int l) {
    int bq = blockIdx.x, b = bq >> 2, q = bq & 3;
    int tid = threadIdx.x, w = tid >> 6, lane = tid & 63;
    int mt = q * 4 + w;
    f32x4 acc[8];
#pragma unroll
    for (int n = 0; n < 8; ++n) acc[n] = (f32x4){0.f, 0.f, 0.f, 0.f};
#pragma unroll
    for (int kt = 0; kt < 8; ++kt) {
        bf16x8 a = *(const bf16x8*)(w1t + ((size_t)((l * 8 + kt) * 16 + mt) * 64 + lane) * 8);
#pragma unroll
        for (int n = 0; n < 8; ++n) {
            int j = n * 16 + (lane & 15);
            bf16x8 bt = *(const bf16x8*)(hnbf + ((size_t)(b * 128 + j) * 256 + kt * 32 + (lane >> 4) * 8));
            acc[n] = __builtin_amdgcn_mfma_f32_16x16x32_bf16(a, bt, acc[n], 0, 0, 0);
        }
    }
    f32x4 bv = *(const f32x4*)(bias1 + l * 256 + mt * 16 + (lane >> 4) * 4);
    float* outb = hn1p + (size_t)b * 32768;
#pragma unroll
    for (int n = 0; n < 8; ++n) {
        f32x4 o = acc[n] + bv;
        *(f32x4*)(outb + ((size_t)(mt * 8 + n) * 64 + lane) * 4) = o;
    }
}

// THE money kernel: per (b,i): T1 = relu(edge@Wf1 + hn1'), T2 = relu(T1@W2+b2),
// msg = sum_j adj*T2 ; h = (h+msg)*m.     grid: 1024 x 256, 2 blocks/CU
__global__ __launch_bounds__(256, 2) void k_msg(
        const u16* __restrict__ wf1t, const u16* __restrict__ ef,
        const u16* __restrict__ w2t,  const float* __restrict__ hn1p,
        const float* __restrict__ b2, const int* __restrict__ adj,
        const int* __restrict__ mask, float* __restrict__ h, int l) {

    __shared__ __align__(16) u16  t1S[8 * 8 * 64 * 8];   // 64 KiB fragment-ordered T1
    __shared__ __align__(16) float adjS[128];
    __shared__ __align__(16) float b2S[256];
    __shared__ __align__(16) float msgS[256];

    int bid = blockIdx.x, b = bid >> 7, i = bid & 127;
    int tid = threadIdx.x, w = tid >> 6, lane = tid & 63;

    if (tid < 128) adjS[tid] = (float)adj[(size_t)(b * 128 + i) * 128 + tid];
    b2S[tid] = b2[l * 256 + tid];

    // ---- GEMM1: T1^T = Wf1^T(256x32) @ edge^T(32x128), wave w owns h-slice 64
    const u16* efb = ef + (size_t)(b * 128 + i) * 4096;
    bf16x8 be[8];
#pragma unroll
    for (int n = 0; n < 8; ++n)
        be[n] = *(const bf16x8*)(efb + (n * 64 + lane) * 8);

    const float* hpb = hn1p + (size_t)b * 32768;
#pragma unroll
    for (int m = 0; m < 4; ++m) {
        int mt = w * 4 + m;
        bf16x8 a = *(const bf16x8*)(wf1t + ((size_t)(l * 16 + mt) * 64 + lane) * 8);
#pragma unroll
        for (int n = 0; n < 8; ++n) {
            f32x4 acc = (f32x4){0.f, 0.f, 0.f, 0.f};
            acc = __builtin_amdgcn_mfma_f32_16x16x32_bf16(a, be[n], acc, 0, 0, 0);
            f32x4 hp = *(const f32x4*)(hpb + ((size_t)(mt * 8 + n) * 64 + lane) * 4);
            float v0 = fmaxf(acc[0] + hp[0], 0.f);
            float v1 = fmaxf(acc[1] + hp[1], 0.f);
            float v2 = fmaxf(acc[2] + hp[2], 0.f);
            float v3 = fmaxf(acc[3] + hp[3], 0.f);
            u32 lo = (u32)f2bf(v0) | ((u32)f2bf(v1) << 16);
            u32 hi = (u32)f2bf(v2) | ((u32)f2bf(v3) << 16);
            // scatter into GEMM2 B-fragment order
            int g    = ((mt & 1) << 1) | (lane >> 5);
            int half = (lane >> 4) & 1;
            int kt2  = mt >> 1;
            uint2 pk; pk.x = lo; pk.y = hi;
            *(uint2*)(t1S + ((size_t)((kt2 * 8 + n) * 64) + g * 16 + (lane & 15)) * 8 + half * 4) = pk;
        }
    }
    __syncthreads();

    // ---- GEMM2: T2^T = W2^T(256x256) @ T1^T(256x128)
    f32x4 acc2[4][8];
#pragma unroll
    for (int m = 0; m < 4; ++m)
#pragma unroll
        for (int n = 0; n < 8; ++n) acc2[m][n] = (f32x4){0.f, 0.f, 0.f, 0.f};

#pragma unroll
    for (int kt = 0; kt < 8; ++kt) {
        bf16x8 a2[4];
#pragma unroll
        for (int m = 0; m < 4; ++m)
            a2[m] = *(const bf16x8*)(w2t + ((size_t)((l * 8 + kt) * 16 + (w * 4 + m)) * 64 + lane) * 8);
#pragma unroll
        for (int n = 0; n < 8; ++n) {
            bf16x8 bt = *(const bf16x8*)(t1S + ((size_t)(kt * 8 + n) * 64 + lane) * 8);
#pragma unroll
            for (int m = 0; m < 4; ++m)
                acc2[m][n] = __builtin_amdgcn_mfma_f32_16x16x32_bf16(a2[m], bt, acc2[m][n], 0, 0, 0);
        }
    }

    // ---- epilogue: relu(+b2) * adj, sum over j (8 nt tiles + 16 lanes)
#pragma unroll
    for (int m = 0; m < 4; ++m) {
        int hb = (w * 4 + m) * 16 + (lane >> 4) * 4;
        f32x4 bv = *(const f32x4*)(&b2S[hb]);
        f32x4 ms = (f32x4){0.f, 0.f, 0.f, 0.f};
#pragma unroll
        for (int n = 0; n < 8; ++n) {
            float aw = adjS[n * 16 + (lane & 15)];
#pragma unroll
            for (int r = 0; r < 4; ++r)
                ms[r] += fmaxf(acc2[m][n][r] + bv[r], 0.f) * aw;
        }
#pragma unroll
        for (int r = 0; r < 4; ++r) {
            ms[r] += __shfl_xor(ms[r], 1);
            ms[r] += __shfl_xor(ms[r], 2);
            ms[r] += __shfl_xor(ms[r], 4);
            ms[r] += __shfl_xor(ms[r], 8);
        }
        if ((lane & 15) == 0) *(f32x4*)(&msgS[hb]) = ms;
    }
    __syncthreads();
    float mv = (float)mask[b * 128 + i];
    size_t row = (size_t)(b * 128 + i) * 256;
    h[row + tid] = (h[row + tid] + msgS[tid]) * mv;
}

// ---------------- readout ----------------

// scores[b,n] = tanh(h@ro_pW + ro_pb) @ ro_aW + ro_ab     grid: 128 x 256
__global__ void k_ro1(const float* __restrict__ h, const float* __restrict__ pW,
                      const float* __restrict__ pb, const float* __restrict__ aW,
                      const float* __restrict__ ab, float* __restrict__ scores) {
    __shared__ float hr[8][256];
    __shared__ float red[4][8];
    int blk = blockIdx.x, b = blk >> 4, g = blk & 15;
    int tid = threadIdx.x;
    size_t base = (size_t)(b * 128 + g * 8) * 256;
#pragma unroll
    for (int t = 0; t < 8; ++t) hr[t][tid] = h[base + t * 256 + tid];
    __syncthreads();
    float facc[8];
    float pbv = pb[tid];
#pragma unroll
    for (int j = 0; j < 8; ++j) facc[j] = pbv;
    for (int k = 0; k < 256; ++k) {
        float wv = pW[(size_t)k * 256 + tid];
#pragma unroll
        for (int j = 0; j < 8; ++j) facc[j] += hr[j][k] * wv;
    }
    float awc = aW[tid];
    int w = tid >> 6, lane = tid & 63;
#pragma unroll
    for (int j = 0; j < 8; ++j) {
        float v = tanhf(facc[j]) * awc;
#pragma unroll
        for (int off = 32; off; off >>= 1) v += __shfl_xor(v, off);
        if (lane == 0) red[w][j] = v;
    }
    __syncthreads();
    if (tid < 8)
        scores[b * 128 + g * 8 + tid] = red[0][tid] + red[1][tid] + red[2][tid] + red[3][tid] + ab[0];
}

// masked softmax + weighted pool + final linear      grid: 8 x 256
__global__ void k_ro2(const float* __restrict__ h, const float* __restrict__ scores,
                      const int* __restrict__ mask, const float* __restrict__ phW,
                      const float* __restrict__ phb, float* __restrict__ out) {
    __shared__ float aS[128];
    __shared__ float rm[4], rc[4], red[4];
    int b = blockIdx.x, tid = threadIdx.x, w = tid >> 6, lane = tid & 63;
    float mv = 0.f, sv = -__builtin_inff();
    if (tid < 128) {
        mv = (float)mask[b * 128 + tid];
        if (mv > 0.f) sv = scores[b * 128 + tid];
    }
    float mx = sv, cs = mv;
#pragma unroll
    for (int off = 32; off; off >>= 1) {
        mx = fmaxf(mx, __shfl_xor(mx, off));
        cs += __shfl_xor(cs, off);
    }
    if (lane == 0) { rm[w] = mx; rc[w] = cs; }
    __syncthreads();
    mx = fmaxf(fmaxf(rm[0], rm[1]), fmaxf(rm[2], rm[3]));
    float cnt = rc[0] + rc[1] + rc[2] + rc[3];
    float e = (tid < 128 && mv > 0.f) ? expf(sv - mx) : 0.f;
    float se = e;
#pragma unroll
    for (int off = 32; off; off >>= 1) se += __shfl_xor(se, off);
    if (lane == 0) red[w] = se;
    __syncthreads();
    float S = red[0] + red[1] + red[2] + red[3];
    if (tid < 128) {
        float a;
        if (S > 0.f) a = e / S;
        else         a = (mv > 0.f) ? 1.f / fmaxf(cnt, 1.f) : 0.f;
        aS[tid] = a;
    }
    __syncthreads();
    float g = 0.f;
    const float* hb = h + (size_t)b * 128 * 256;
    for (int n = 0; n < 128; ++n) g += aS[n] * hb[(size_t)n * 256 + tid];
    float p = g * phW[tid];
#pragma unroll
    for (int off = 32; off; off >>= 1) p += __shfl_xor(p, off);
    __syncthreads();                       // red[] reads above are done
    if (lane == 0) red[w] = p;
    __syncthreads();
    if (tid == 0) out[b] = red[0] + red[1] + red[2] + red[3] + phb[0];
}

// ---------------- host ----------------
extern "C" void kernel_launch(void* const* d_in, const int* in_sizes, int n_in,
                              void* d_out, int out_size, void* d_ws, size_t ws_size,
                              hipStream_t stream) {
    const float* x    = (const float*)d_in[0];
    const int*   adj  = (const int*)  d_in[1];
    const float* ea   = (const float*)d_in[2];
    const int*   mask = (const int*)  d_in[3];
    const float* nW   = (const float*)d_in[4];
    const float* nb   = (const float*)d_in[5];
    const float* eW   = (const float*)d_in[6];
    const float* eb   = (const float*)d_in[7];
    const float* lng  = (const float*)d_in[8];
    const float* lnb  = (const float*)d_in[9];
    const float* W1   = (const float*)d_in[10];
    const float* b1   = (const float*)d_in[11];
    const float* W2   = (const float*)d_in[12];
    const float* b2   = (const float*)d_in[13];
    const float* ropW = (const float*)d_in[14];
    const float* ropb = (const float*)d_in[15];
    const float* roaW = (const float*)d_in[16];
    const float* roab = (const float*)d_in[17];
    const float* phW  = (const float*)d_in[18];
    const float* phb  = (const float*)d_in[19];
    float* out = (float*)d_out;

    char* p = (char*)d_ws;
    auto alloc = [&](size_t bytes) { char* r = p; p += (bytes + 255) & ~(size_t)255; return r; };
    float* h     = (float*)alloc((size_t)8 * 128 * 256 * 4);      // 1 MB
    u16*   hnbf  = (u16*)  alloc((size_t)8 * 128 * 256 * 2);      // 512 KB
    float* hn1p  = (float*)alloc((size_t)8 * 32768 * 4);          // 1 MB
    u16*   ef    = (u16*)  alloc((size_t)8 * 128 * 4096 * 2);     // 8 MB
    u16*   wf1t  = (u16*)  alloc((size_t)8 * 16 * 64 * 8 * 2);    // 128 KB
    u16*   w1t   = (u16*)  alloc((size_t)8 * 8 * 16 * 64 * 8 * 2);// 1 MB
    u16*   w2t   = (u16*)  alloc((size_t)8 * 8 * 16 * 64 * 8 * 2);// 1 MB
    float* bias1 = (float*)alloc((size_t)8 * 256 * 4);
    float* scores= (float*)alloc((size_t)1024 * 4);

    k_h0      <<<1024, 256, 0, stream>>>(x, nW, nb, h);
    k_edgefrag<<<2048, 256, 0, stream>>>(ea, ef);
    k_wf1     <<<32,   256, 0, stream>>>(eW, W1, wf1t);
    k_wt      <<<256,  256, 0, stream>>>(W1, W2, w1t, w2t);
    k_bias1   <<<8,    256, 0, stream>>>(eb, W1, b1, bias1);

    for (int l = 0; l < 8; ++l) {
        k_ln <<<1024, 256, 0, stream>>>(h, mask, lng, lnb, hnbf, l);
        k_hn1<<<32,   256, 0, stream>>>(w1t, hnbf, bias1, hn1p, l);
        k_msg<<<1024, 256, 0, stream>>>(wf1t, ef, w2t, hn1p, b2, adj, mask, h, l);
    }

    k_ro1<<<128, 256, 0, stream>>>(h, ropW, ropb, roaW, roab, scores);
    k_ro2<<<8,   256, 0, stream>>>(h, scores, mask, phW, phb, out);
}

// Round 2
// 396.300 us; speedup vs baseline: 1.2289x; 1.2289x over previous
//
#include <hip/hip_runtime.h>

// ---------------- common ----------------
typedef float  f32x4  __attribute__((ext_vector_type(4)));
typedef short  bf16x8 __attribute__((ext_vector_type(8)));
typedef unsigned short u16;
typedef unsigned int   u32;

static __device__ __forceinline__ u16 f2bf(float f) {   // RNE float -> bf16
    u32 u = __float_as_uint(f);
    u += 0x7FFFu + ((u >> 16) & 1u);
    return (u16)(u >> 16);
}

// dims: B=8 N=128 F_IN=64 F_E=16 H=256 L=8

// ---------------- setup kernels ----------------

// h0 = x @ node_W + node_b       grid: 1024 x 256
__global__ void k_h0(const float* __restrict__ x, const float* __restrict__ nW,
                     const float* __restrict__ nb, float* __restrict__ h) {
    __shared__ float xr[64];
    int row = blockIdx.x, c = threadIdx.x;
    if (c < 64) xr[c] = x[row * 64 + c];
    __syncthreads();
    float acc = nb[c];
#pragma unroll
    for (int k = 0; k < 64; ++k) acc += xr[k] * nW[k * 256 + c];
    h[row * 256 + c] = acc;
}

// edge_attr -> bf16 fragment layout, K padded 16->32 with zeros.
// ef[((b*128+i)*8 + nt)*64 + lane][8]   j = nt*16+(lane&15), k0=(lane>>4)*8
__global__ void k_edgefrag(const float* __restrict__ ea, u16* __restrict__ ef) {
    int gid = blockIdx.x * 256 + threadIdx.x;
    int lane = gid & 63, nt = (gid >> 6) & 7, i = (gid >> 9) & 127, b = gid >> 16;
    int j = nt * 16 + (lane & 15), k0 = (lane >> 4) * 8;
    uint4 out = {0u, 0u, 0u, 0u};
    if (k0 < 16) {
        const float* p = ea + (((size_t)(b * 128 + i) * 128 + j) * 16 + k0);
        u16 us[8];
#pragma unroll
        for (int t = 0; t < 8; ++t) us[t] = f2bf(p[t]);
        out.x = (u32)us[0] | ((u32)us[1] << 16);
        out.y = (u32)us[2] | ((u32)us[3] << 16);
        out.z = (u32)us[4] | ((u32)us[5] << 16);
        out.w = (u32)us[6] | ((u32)us[7] << 16);
    }
    ((uint4*)ef)[gid] = out;
}

// W1^T / W2^T fragment packs: wt[((l*8+kt)*16+mt)*64+lane][8]
__global__ void k_wt(const float* __restrict__ W1, const float* __restrict__ W2,
                     u16* __restrict__ w1t, u16* __restrict__ w2t) {
    int gid = blockIdx.x * 256 + threadIdx.x;
    int lane = gid & 63, mt = (gid >> 6) & 15, kt = (gid >> 10) & 7, l = gid >> 13;
    int hh = mt * 16 + (lane & 15), k = kt * 32 + (lane >> 4) * 8;
    u16 a[8], b[8];
#pragma unroll
    for (int t = 0; t < 8; ++t) {
        size_t idx = (size_t)l * 65536 + (size_t)(k + t) * 256 + hh;
        a[t] = f2bf(W1[idx]);
        b[t] = f2bf(W2[idx]);
    }
    uint4 oa, ob;
    oa.x = (u32)a[0] | ((u32)a[1] << 16); oa.y = (u32)a[2] | ((u32)a[3] << 16);
    oa.z = (u32)a[4] | ((u32)a[5] << 16); oa.w = (u32)a[6] | ((u32)a[7] << 16);
    ob.x = (u32)b[0] | ((u32)b[1] << 16); ob.y = (u32)b[2] | ((u32)b[3] << 16);
    ob.z = (u32)b[4] | ((u32)b[5] << 16); ob.w = (u32)b[6] | ((u32)b[7] << 16);
    ((uint4*)w1t)[gid] = oa;
    ((uint4*)w2t)[gid] = ob;
}

// Wf1 = edge_W @ W1[l] (A-fragment pack) AND bias1 = edge_b @ W1[l] + b1[l]
// grid: 8 blocks (one per l) x 256 threads (thread = h')
__global__ void k_wf1b(const float* __restrict__ eW, const float* __restrict__ eb,
                       const float* __restrict__ W1, const float* __restrict__ b1,
                       u16* __restrict__ wf, float* __restrict__ bias1) {
    __shared__ float eWsT[256 * 16];   // [c][k]
    __shared__ float ebS[256];
    int l = blockIdx.x, tid = threadIdx.x;
#pragma unroll
    for (int k = 0; k < 16; ++k) eWsT[tid * 16 + k] = eW[k * 256 + tid];
    ebS[tid] = eb[tid];
    __syncthreads();
    float acc[16];
#pragma unroll
    for (int k = 0; k < 16; ++k) acc[k] = 0.f;
    float bacc = b1[l * 256 + tid];
    const float* w1c = W1 + (size_t)l * 65536 + tid;
    for (int c = 0; c < 256; ++c) {
        float wv = w1c[(size_t)c * 256];
        const f32x4* e = (const f32x4*)&eWsT[c * 16];
#pragma unroll
        for (int q = 0; q < 4; ++q) {
            f32x4 ev = e[q];
#pragma unroll
            for (int t = 0; t < 4; ++t) acc[q * 4 + t] += ev[t] * wv;
        }
        bacc += ebS[c] * wv;
    }
    bias1[l * 256 + tid] = bacc;
    int mt = tid >> 4, lo = tid & 15;
#pragma unroll
    for (int c4 = 0; c4 < 4; ++c4) {
        u16 us[8];
#pragma unroll
        for (int t = 0; t < 8; ++t) {
            int k = c4 * 8 + t;
            us[t] = (k < 16) ? f2bf(acc[k]) : (u16)0;
        }
        uint4 o;
        o.x = (u32)us[0] | ((u32)us[1] << 16);
        o.y = (u32)us[2] | ((u32)us[3] << 16);
        o.z = (u32)us[4] | ((u32)us[5] << 16);
        o.w = (u32)us[6] | ((u32)us[7] << 16);
        ((uint4*)wf)[(size_t)(l * 16 + mt) * 64 + c4 * 16 + lo] = o;
    }
}

// ---------------- per-layer kernels ----------------

// initial mask + layernorm -> bf16 rows (layer 0 only).   grid: 1024 x 256
__global__ void k_ln(float* __restrict__ h, const int* __restrict__ mask,
                     const float* __restrict__ lng, const float* __restrict__ lnb,
                     u16* __restrict__ hnbf) {
    __shared__ float rs[4], rs2[4];
    int row = blockIdx.x, c = threadIdx.x;
    float mv = (float)mask[row];
    float v = h[row * 256 + c] * mv;
    h[row * 256 + c] = v;
    float s = v, s2 = v * v;
    int w = c >> 6, lane = c & 63;
#pragma unroll
    for (int off = 32; off; off >>= 1) {
        s  += __shfl_xor(s,  off);
        s2 += __shfl_xor(s2, off);
    }
    if (lane == 0) { rs[w] = s; rs2[w] = s2; }
    __syncthreads();
    float S  = rs[0] + rs[1] + rs[2] + rs[3];
    float S2 = rs2[0] + rs2[1] + rs2[2] + rs2[3];
    float mu  = S * (1.f / 256.f);
    float var = S2 * (1.f / 256.f) - mu * mu;
    float rstd = rsqrtf(var + 1e-5f);
    hnbf[row * 256 + c] = f2bf((v - mu) * rstd * lng[c] + lnb[c]);
}

// hn1' = h_norm @ W1[l] + bias1[l] (transposed, fragment-permuted output)
// grid: 64 x 256  (block = (b, mt-pair))
__global__ __launch_bounds__(256) void k_hn1(const u16* __restrict__ w1t,
        const u16* __restrict__ hnbf, const float* __restrict__ bias1,
        float* __restrict__ hn1p, int l) {
    int orig = blockIdx.x;
    int bid = (orig & 7) * 8 + (orig >> 3);       // XCD swizzle: b per XCD
    int b = bid >> 3, q = bid & 7;
    int tid = threadIdx.x, w = tid >> 6, lane = tid & 63;
    int mt = q * 2 + (w >> 1), nb_ = (w & 1) * 4;
    f32x4 bv = *(const f32x4*)(bias1 + l * 256 + mt * 16 + (lane >> 4) * 4);
    f32x4 acc[4];
#pragma unroll
    for (int n = 0; n < 4; ++n) acc[n] = bv;
#pragma unroll
    for (int kt = 0; kt < 8; ++kt) {
        bf16x8 a = *(const bf16x8*)(w1t + ((size_t)((l * 8 + kt) * 16 + mt) * 64 + lane) * 8);
#pragma unroll
        for (int nn = 0; nn < 4; ++nn) {
            int j = (nb_ + nn) * 16 + (lane & 15);
            bf16x8 bt = *(const bf16x8*)(hnbf + ((size_t)(b * 128 + j) * 256 + kt * 32 + (lane >> 4) * 8));
            acc[nn] = __builtin_amdgcn_mfma_f32_16x16x32_bf16(a, bt, acc[nn], 0, 0, 0);
        }
    }
    float* outb = hn1p + (size_t)b * 32768;
#pragma unroll
    for (int nn = 0; nn < 4; ++nn)
        *(f32x4*)(outb + ((size_t)(mt * 8 + nb_ + nn) * 64 + lane) * 4) = acc[nn];
}

// money kernel: per (b,i): T1=relu(edge@Wf1+hn1'), T2=relu(T1@W2+b2),
// msg=sum_j adj*T2; h=(h+msg)*m; fused LN of next layer.
// grid: 1024 x 512 (8 waves), 2 blocks/CU (66.5KB LDS), 4 waves/SIMD
__global__ __launch_bounds__(512, 4) void k_msg(
        const u16* __restrict__ wf1t, const u16* __restrict__ ef,
        const u16* __restrict__ w2t,  const float* __restrict__ hn1p,
        const float* __restrict__ b2, const int* __restrict__ adj,
        const int* __restrict__ mask, float* __restrict__ h,
        const float* __restrict__ lngN, const float* __restrict__ lnbN,
        u16* __restrict__ hnbf, int l, int doLN) {

    __shared__ __align__(16) u16  t1S[8 * 8 * 64 * 8];   // 64 KiB
    __shared__ __align__(16) float adjS[128];
    __shared__ __align__(16) float b2S[256];
    __shared__ __align__(16) float msgS[256];
    __shared__ float rs[8], rs2[8];

    int orig = blockIdx.x;
    int bid = (orig & 7) * 128 + (orig >> 3);     // XCD swizzle: b per XCD
    int b = bid >> 7, i = bid & 127;
    int tid = threadIdx.x, w = tid >> 6, lane = tid & 63;
    int row = b * 128 + i;

    if (tid < 128) adjS[tid] = (float)adj[(size_t)row * 128 + tid];
    if (tid < 256) b2S[tid] = b2[l * 256 + tid];

    // ---- GEMM1: T1^T = Wf1^T(256x32) @ edge^T(32x128); wave w: mt in {2w,2w+1}
    const u16* efb = ef + (size_t)row * 4096;
    bf16x8 be[8];
#pragma unroll
    for (int n = 0; n < 8; ++n)
        be[n] = *(const bf16x8*)(efb + (n * 64 + lane) * 8);

    const float* hpb = hn1p + (size_t)b * 32768;
#pragma unroll
    for (int m = 0; m < 2; ++m) {
        int mt = w * 2 + m;
        bf16x8 a = *(const bf16x8*)(wf1t + ((size_t)(l * 16 + mt) * 64 + lane) * 8);
#pragma unroll
        for (int n = 0; n < 8; ++n) {
            f32x4 acc = *(const f32x4*)(hpb + ((size_t)(mt * 8 + n) * 64 + lane) * 4);
            acc = __builtin_amdgcn_mfma_f32_16x16x32_bf16(a, be[n], acc, 0, 0, 0);
            u32 lo = (u32)f2bf(fmaxf(acc[0], 0.f)) | ((u32)f2bf(fmaxf(acc[1], 0.f)) << 16);
            u32 hi = (u32)f2bf(fmaxf(acc[2], 0.f)) | ((u32)f2bf(fmaxf(acc[3], 0.f)) << 16);
            int g    = ((mt & 1) << 1) | (lane >> 5);
            int half = (lane >> 4) & 1;
            uint2 pk; pk.x = lo; pk.y = hi;
            *(uint2*)(t1S + ((size_t)(((mt >> 1) * 8 + n) * 64) + g * 16 + (lane & 15)) * 8 + half * 4) = pk;
        }
    }
    __syncthreads();

    // ---- GEMM2: T2^T = W2^T(256x256) @ T1^T(256x128); wave w: mt' in {2w,2w+1}
    f32x4 acc2[2][8];
#pragma unroll
    for (int m = 0; m < 2; ++m)
#pragma unroll
        for (int n = 0; n < 8; ++n) acc2[m][n] = (f32x4){0.f, 0.f, 0.f, 0.f};

#pragma unroll
    for (int kt = 0; kt < 8; ++kt) {
        bf16x8 a2[2];
#pragma unroll
        for (int m = 0; m < 2; ++m)
            a2[m] = *(const bf16x8*)(w2t + ((size_t)((l * 8 + kt) * 16 + (w * 2 + m)) * 64 + lane) * 8);
#pragma unroll
        for (int n = 0; n < 8; ++n) {
            bf16x8 bt = *(const bf16x8*)(t1S + ((size_t)(kt * 8 + n) * 64 + lane) * 8);
#pragma unroll
            for (int m = 0; m < 2; ++m)
                acc2[m][n] = __builtin_amdgcn_mfma_f32_16x16x32_bf16(a2[m], bt, acc2[m][n], 0, 0, 0);
        }
    }

    // ---- epilogue: relu(+b2) * adj, reduce over j
#pragma unroll
    for (int m = 0; m < 2; ++m) {
        int hb = (w * 2 + m) * 16 + (lane >> 4) * 4;
        f32x4 bv = *(const f32x4*)(&b2S[hb]);
        f32x4 ms = (f32x4){0.f, 0.f, 0.f, 0.f};
#pragma unroll
        for (int n = 0; n < 8; ++n) {
            float aw = adjS[n * 16 + (lane & 15)];
#pragma unroll
            for (int r = 0; r < 4; ++r)
                ms[r] += fmaxf(acc2[m][n][r] + bv[r], 0.f) * aw;
        }
#pragma unroll
        for (int r = 0; r < 4; ++r) {
            ms[r] += __shfl_xor(ms[r], 1);
            ms[r] += __shfl_xor(ms[r], 2);
            ms[r] += __shfl_xor(ms[r], 4);
            ms[r] += __shfl_xor(ms[r], 8);
        }
        if ((lane & 15) == 0) *(f32x4*)(&msgS[hb]) = ms;
    }
    __syncthreads();

    // ---- tail: residual + mask, then fused LN for next layer
    float v = 0.f;
    if (tid < 256) {
        float mv = (float)mask[row];
        v = (h[(size_t)row * 256 + tid] + msgS[tid]) * mv;
        h[(size_t)row * 256 + tid] = v;
    }
    float s = v, s2 = v * v;
#pragma unroll
    for (int off = 32; off; off >>= 1) {
        s  += __shfl_xor(s,  off);
        s2 += __shfl_xor(s2, off);
    }
    if (lane == 0) { rs[w] = s; rs2[w] = s2; }
    __syncthreads();
    if (doLN && tid < 256) {
        float S = 0.f, S2 = 0.f;
#pragma unroll
        for (int t = 0; t < 8; ++t) { S += rs[t]; S2 += rs2[t]; }
        float mu  = S * (1.f / 256.f);
        float var = S2 * (1.f / 256.f) - mu * mu;
        float rstd = rsqrtf(var + 1e-5f);
        hnbf[(size_t)row * 256 + tid] = f2bf((v - mu) * rstd * lngN[tid] + lnbN[tid]);
    }
}

// ---------------- readout ----------------

__global__ void k_ro1(const float* __restrict__ h, const float* __restrict__ pW,
                      const float* __restrict__ pb, const float* __restrict__ aW,
                      const float* __restrict__ ab, float* __restrict__ scores) {
    __shared__ float hr[8][256];
    __shared__ float red[4][8];
    int blk = blockIdx.x, b = blk >> 4, g = blk & 15;
    int tid = threadIdx.x;
    size_t base = (size_t)(b * 128 + g * 8) * 256;
#pragma unroll
    for (int t = 0; t < 8; ++t) hr[t][tid] = h[base + t * 256 + tid];
    __syncthreads();
    float facc[8];
    float pbv = pb[tid];
#pragma unroll
    for (int j = 0; j < 8; ++j) facc[j] = pbv;
    for (int k = 0; k < 256; ++k) {
        float wv = pW[(size_t)k * 256 + tid];
#pragma unroll
        for (int j = 0; j < 8; ++j) facc[j] += hr[j][k] * wv;
    }
    float awc = aW[tid];
    int w = tid >> 6, lane = tid & 63;
#pragma unroll
    for (int j = 0; j < 8; ++j) {
        float v = tanhf(facc[j]) * awc;
#pragma unroll
        for (int off = 32; off; off >>= 1) v += __shfl_xor(v, off);
        if (lane == 0) red[w][j] = v;
    }
    __syncthreads();
    if (tid < 8)
        scores[b * 128 + g * 8 + tid] = red[0][tid] + red[1][tid] + red[2][tid] + red[3][tid] + ab[0];
}

__global__ void k_ro2(const float* __restrict__ h, const float* __restrict__ scores,
                      const int* __restrict__ mask, const float* __restrict__ phW,
                      const float* __restrict__ phb, float* __restrict__ out) {
    __shared__ float aS[128];
    __shared__ float rm[4], rc[4], red[4];
    int b = blockIdx.x, tid = threadIdx.x, w = tid >> 6, lane = tid & 63;
    float mv = 0.f, sv = -__builtin_inff();
    if (tid < 128) {
        mv = (float)mask[b * 128 + tid];
        if (mv > 0.f) sv = scores[b * 128 + tid];
    }
    float mx = sv, cs = mv;
#pragma unroll
    for (int off = 32; off; off >>= 1) {
        mx = fmaxf(mx, __shfl_xor(mx, off));
        cs += __shfl_xor(cs, off);
    }
    if (lane == 0) { rm[w] = mx; rc[w] = cs; }
    __syncthreads();
    mx = fmaxf(fmaxf(rm[0], rm[1]), fmaxf(rm[2], rm[3]));
    float cnt = rc[0] + rc[1] + rc[2] + rc[3];
    float e = (tid < 128 && mv > 0.f) ? expf(sv - mx) : 0.f;
    float se = e;
#pragma unroll
    for (int off = 32; off; off >>= 1) se += __shfl_xor(se, off);
    if (lane == 0) red[w] = se;
    __syncthreads();
    float S = red[0] + red[1] + red[2] + red[3];
    if (tid < 128) {
        float a;
        if (S > 0.f) a = e / S;
        else         a = (mv > 0.f) ? 1.f / fmaxf(cnt, 1.f) : 0.f;
        aS[tid] = a;
    }
    __syncthreads();
    float g = 0.f;
    const float* hb = h + (size_t)b * 128 * 256;
    for (int n = 0; n < 128; ++n) g += aS[n] * hb[(size_t)n * 256 + tid];
    float p = g * phW[tid];
#pragma unroll
    for (int off = 32; off; off >>= 1) p += __shfl_xor(p, off);
    __syncthreads();
    if (lane == 0) red[w] = p;
    __syncthreads();
    if (tid == 0) out[b] = red[0] + red[1] + red[2] + red[3] + phb[0];
}

// ---------------- host ----------------
extern "C" void kernel_launch(void* const* d_in, const int* in_sizes, int n_in,
                              void* d_out, int out_size, void* d_ws, size_t ws_size,
                              hipStream_t stream) {
    const float* x    = (const float*)d_in[0];
    const int*   adj  = (const int*)  d_in[1];
    const float* ea   = (const float*)d_in[2];
    const int*   mask = (const int*)  d_in[3];
    const float* nW   = (const float*)d_in[4];
    const float* nb   = (const float*)d_in[5];
    const float* eW   = (const float*)d_in[6];
    const float* eb   = (const float*)d_in[7];
    const float* lng  = (const float*)d_in[8];
    const float* lnb  = (const float*)d_in[9];
    const float* W1   = (const float*)d_in[10];
    const float* b1   = (const float*)d_in[11];
    const float* W2   = (const float*)d_in[12];
    const float* b2   = (const float*)d_in[13];
    const float* ropW = (const float*)d_in[14];
    const float* ropb = (const float*)d_in[15];
    const float* roaW = (const float*)d_in[16];
    const float* roab = (const float*)d_in[17];
    const float* phW  = (const float*)d_in[18];
    const float* phb  = (const float*)d_in[19];
    float* out = (float*)d_out;

    char* p = (char*)d_ws;
    auto alloc = [&](size_t bytes) { char* r = p; p += (bytes + 255) & ~(size_t)255; return r; };
    float* h     = (float*)alloc((size_t)8 * 128 * 256 * 4);
    u16*   hnbf  = (u16*)  alloc((size_t)8 * 128 * 256 * 2);
    float* hn1p  = (float*)alloc((size_t)8 * 32768 * 4);
    u16*   ef    = (u16*)  alloc((size_t)8 * 128 * 4096 * 2);
    u16*   wf1t  = (u16*)  alloc((size_t)8 * 16 * 64 * 8 * 2);
    u16*   w1t   = (u16*)  alloc((size_t)8 * 8 * 16 * 64 * 8 * 2);
    u16*   w2t   = (u16*)  alloc((size_t)8 * 8 * 16 * 64 * 8 * 2);
    float* bias1 = (float*)alloc((size_t)8 * 256 * 4);
    float* scores= (float*)alloc((size_t)1024 * 4);

    k_h0      <<<1024, 256, 0, stream>>>(x, nW, nb, h);
    k_edgefrag<<<2048, 256, 0, stream>>>(ea, ef);
    k_wt      <<<256,  256, 0, stream>>>(W1, W2, w1t, w2t);
    k_wf1b    <<<8,    256, 0, stream>>>(eW, eb, W1, b1, wf1t, bias1);
    k_ln      <<<1024, 256, 0, stream>>>(h, mask, lng, lnb, hnbf);

    for (int l = 0; l < 8; ++l) {
        k_hn1<<<64,   256, 0, stream>>>(w1t, hnbf, bias1, hn1p, l);
        int doLN = (l < 7) ? 1 : 0;
        int ln_next = (l < 7) ? (l + 1) : l;
        k_msg<<<1024, 512, 0, stream>>>(wf1t, ef, w2t, hn1p, b2, adj, mask, h,
                                        lng + ln_next * 256, lnb + ln_next * 256,
                                        hnbf, l, doLN);
    }

    k_ro1<<<128, 256, 0, stream>>>(h, ropW, ropb, roaW, roab, scores);
    k_ro2<<<8,   256, 0, stream>>>(h, scores, mask, phW, phb, out);
}

// Round 3
// 355.801 us; speedup vs baseline: 1.3688x; 1.1138x over previous
//
#include <hip/hip_runtime.h>

// ---------------- common ----------------
typedef float  f32x4  __attribute__((ext_vector_type(4)));
typedef short  bf16x8 __attribute__((ext_vector_type(8)));
typedef unsigned short u16;
typedef unsigned int   u32;

static __device__ __forceinline__ u16 f2bf(float f) {   // RNE float -> bf16
    u32 u = __float_as_uint(f);
    u += 0x7FFFu + ((u >> 16) & 1u);
    return (u16)(u >> 16);
}

// dims: B=8 N=128 F_IN=64 F_E=16 H=256 L=8

// ---------------- setup kernels ----------------

// h0 = x @ node_W + node_b, then mask + layernorm(l=0) -> bf16.  grid: 1024 x 256
__global__ void k_h0ln(const float* __restrict__ x, const float* __restrict__ nW,
                       const float* __restrict__ nb, const int* __restrict__ mask,
                       const float* __restrict__ lng, const float* __restrict__ lnb,
                       float* __restrict__ h, u16* __restrict__ hnbf) {
    __shared__ float xr[64];
    __shared__ float rs[4], rs2[4];
    int row = blockIdx.x, c = threadIdx.x;
    if (c < 64) xr[c] = x[row * 64 + c];
    __syncthreads();
    float acc = nb[c];
#pragma unroll
    for (int k = 0; k < 64; ++k) acc += xr[k] * nW[k * 256 + c];
    float mv = (float)mask[row];
    float v = acc * mv;
    h[row * 256 + c] = v;
    float s = v, s2 = v * v;
    int w = c >> 6, lane = c & 63;
#pragma unroll
    for (int off = 32; off; off >>= 1) {
        s  += __shfl_xor(s,  off);
        s2 += __shfl_xor(s2, off);
    }
    if (lane == 0) { rs[w] = s; rs2[w] = s2; }
    __syncthreads();
    float S  = rs[0] + rs[1] + rs[2] + rs[3];
    float S2 = rs2[0] + rs2[1] + rs2[2] + rs2[3];
    float mu  = S * (1.f / 256.f);
    float var = S2 * (1.f / 256.f) - mu * mu;
    float rstd = rsqrtf(var + 1e-5f);
    hnbf[row * 256 + c] = f2bf((v - mu) * rstd * lng[c] + lnb[c]);
}

// edge_attr -> bf16 fragment layout, K padded 16->32 with zeros.
// ef[((b*128+i)*8 + nt)*64 + lane][8]   j = nt*16+(lane&15), k0=(lane>>4)*8
__global__ void k_edgefrag(const float* __restrict__ ea, u16* __restrict__ ef) {
    int gid = blockIdx.x * 256 + threadIdx.x;
    int lane = gid & 63, nt = (gid >> 6) & 7, i = (gid >> 9) & 127, b = gid >> 16;
    int j = nt * 16 + (lane & 15), k0 = (lane >> 4) * 8;
    uint4 out = {0u, 0u, 0u, 0u};
    if (k0 < 16) {
        const float* p = ea + (((size_t)(b * 128 + i) * 128 + j) * 16 + k0);
        u16 us[8];
#pragma unroll
        for (int t = 0; t < 8; ++t) us[t] = f2bf(p[t]);
        out.x = (u32)us[0] | ((u32)us[1] << 16);
        out.y = (u32)us[2] | ((u32)us[3] << 16);
        out.z = (u32)us[4] | ((u32)us[5] << 16);
        out.w = (u32)us[6] | ((u32)us[7] << 16);
    }
    ((uint4*)ef)[gid] = out;
}

// W1^T / W2^T fragment packs: wt[((l*8+kt)*16+mt)*64+lane][8]
__global__ void k_wt(const float* __restrict__ W1, const float* __restrict__ W2,
                     u16* __restrict__ w1t, u16* __restrict__ w2t) {
    int gid = blockIdx.x * 256 + threadIdx.x;
    int lane = gid & 63, mt = (gid >> 6) & 15, kt = (gid >> 10) & 7, l = gid >> 13;
    int hh = mt * 16 + (lane & 15), k = kt * 32 + (lane >> 4) * 8;
    u16 a[8], b[8];
#pragma unroll
    for (int t = 0; t < 8; ++t) {
        size_t idx = (size_t)l * 65536 + (size_t)(k + t) * 256 + hh;
        a[t] = f2bf(W1[idx]);
        b[t] = f2bf(W2[idx]);
    }
    uint4 oa, ob;
    oa.x = (u32)a[0] | ((u32)a[1] << 16); oa.y = (u32)a[2] | ((u32)a[3] << 16);
    oa.z = (u32)a[4] | ((u32)a[5] << 16); oa.w = (u32)a[6] | ((u32)a[7] << 16);
    ob.x = (u32)b[0] | ((u32)b[1] << 16); ob.y = (u32)b[2] | ((u32)b[3] << 16);
    ob.z = (u32)b[4] | ((u32)b[5] << 16); ob.w = (u32)b[6] | ((u32)b[7] << 16);
    ((uint4*)w1t)[gid] = oa;
    ((uint4*)w2t)[gid] = ob;
}

// Wf1 = edge_W @ W1[l] (A-fragment pack) AND bias1 = edge_b @ W1[l] + b1[l]
// grid: 8 blocks (one per l) x 256 threads (thread = h')
__global__ void k_wf1b(const float* __restrict__ eW, const float* __restrict__ eb,
                       const float* __restrict__ W1, const float* __restrict__ b1,
                       u16* __restrict__ wf, float* __restrict__ bias1) {
    __shared__ float eWsT[256 * 16];   // [c][k]
    __shared__ float ebS[256];
    int l = blockIdx.x, tid = threadIdx.x;
#pragma unroll
    for (int k = 0; k < 16; ++k) eWsT[tid * 16 + k] = eW[k * 256 + tid];
    ebS[tid] = eb[tid];
    __syncthreads();
    float acc[16];
#pragma unroll
    for (int k = 0; k < 16; ++k) acc[k] = 0.f;
    float bacc = b1[l * 256 + tid];
    const float* w1c = W1 + (size_t)l * 65536 + tid;
    for (int c = 0; c < 256; ++c) {
        float wv = w1c[(size_t)c * 256];
        const f32x4* e = (const f32x4*)&eWsT[c * 16];
#pragma unroll
        for (int q = 0; q < 4; ++q) {
            f32x4 ev = e[q];
#pragma unroll
            for (int t = 0; t < 4; ++t) acc[q * 4 + t] += ev[t] * wv;
        }
        bacc += ebS[c] * wv;
    }
    bias1[l * 256 + tid] = bacc;
    int mt = tid >> 4, lo = tid & 15;
#pragma unroll
    for (int c4 = 0; c4 < 4; ++c4) {
        u16 us[8];
#pragma unroll
        for (int t = 0; t < 8; ++t) {
            int k = c4 * 8 + t;
            us[t] = (k < 16) ? f2bf(acc[k]) : (u16)0;
        }
        uint4 o;
        o.x = (u32)us[0] | ((u32)us[1] << 16);
        o.y = (u32)us[2] | ((u32)us[3] << 16);
        o.z = (u32)us[4] | ((u32)us[5] << 16);
        o.w = (u32)us[6] | ((u32)us[7] << 16);
        ((uint4*)wf)[(size_t)(l * 16 + mt) * 64 + c4 * 16 + lo] = o;
    }
}

// ---------------- per-layer kernels ----------------

// hn1' = h_norm @ W1[l] + bias1[l] (transposed, fragment-permuted output)
// grid: 128 x 256  (block = (b, mt))
__global__ __launch_bounds__(256) void k_hn1(const u16* __restrict__ w1t,
        const u16* __restrict__ hnbf, const float* __restrict__ bias1,
        float* __restrict__ hn1p, int l) {
    int orig = blockIdx.x;
    int bid = (orig & 7) * 16 + (orig >> 3);      // XCD swizzle
    int b = bid >> 4, mt = bid & 15;
    int tid = threadIdx.x, w = tid >> 6, lane = tid & 63;
    f32x4 bv = *(const f32x4*)(bias1 + l * 256 + mt * 16 + (lane >> 4) * 4);
    f32x4 acc0 = bv, acc1 = bv;
    int j0 = (w * 2) * 16 + (lane & 15), j1 = j0 + 16;
#pragma unroll
    for (int kt = 0; kt < 8; ++kt) {
        bf16x8 a = *(const bf16x8*)(w1t + ((size_t)((l * 8 + kt) * 16 + mt) * 64 + lane) * 8);
        bf16x8 bt0 = *(const bf16x8*)(hnbf + ((size_t)(b * 128 + j0) * 256 + kt * 32 + (lane >> 4) * 8));
        bf16x8 bt1 = *(const bf16x8*)(hnbf + ((size_t)(b * 128 + j1) * 256 + kt * 32 + (lane >> 4) * 8));
        acc0 = __builtin_amdgcn_mfma_f32_16x16x32_bf16(a, bt0, acc0, 0, 0, 0);
        acc1 = __builtin_amdgcn_mfma_f32_16x16x32_bf16(a, bt1, acc1, 0, 0, 0);
    }
    float* outb = hn1p + (size_t)b * 32768;
    *(f32x4*)(outb + ((size_t)(mt * 8 + w * 2) * 64 + lane) * 4)     = acc0;
    *(f32x4*)(outb + ((size_t)(mt * 8 + w * 2 + 1) * 64 + lane) * 4) = acc1;
}

// money kernel with active-j compaction:
// per (b,i): list = {j : adj[i][j]!=0};  T1=relu(edge@Wf1+hn1') on active tiles,
// T2=relu(T1@W2+b2), msg=sum_active T2; h=(h+msg)*m; fused LN of next layer.
// grid: 1024 x 512 (8 waves), 2 blocks/CU, 4 waves/SIMD
__global__ __launch_bounds__(512, 4) void k_msg(
        const u16* __restrict__ wf1t, const u16* __restrict__ ef,
        const u16* __restrict__ w2t,  const float* __restrict__ hn1p,
        const float* __restrict__ b2, const int* __restrict__ adj,
        const int* __restrict__ mask, float* __restrict__ h,
        const float* __restrict__ lngN, const float* __restrict__ lnbN,
        u16* __restrict__ hnbf, int l, int doLN) {

    __shared__ __align__(16) u16  t1S[8 * 8 * 64 * 8];   // 64 KiB
    __shared__ __align__(16) float b2S[256];
    __shared__ __align__(16) float msgS[256];
    __shared__ int listS[128];
    __shared__ int flagS[128];
    __shared__ int cntS;
    __shared__ float rs[8], rs2[8];

    int orig = blockIdx.x;
    int bid = (orig & 7) * 128 + (orig >> 3);     // XCD swizzle
    int b = bid >> 7, i = bid & 127;
    int tid = threadIdx.x, w = tid >> 6, lane = tid & 63;
    int row = b * 128 + i;

    if (tid < 128) { flagS[tid] = adj[(size_t)row * 128 + tid]; listS[tid] = 0; }
    if (tid < 256) b2S[tid] = b2[l * 256 + tid];
    __syncthreads();

    if (w == 0) {   // active-j compaction (order-preserving), one wave
        int f0 = flagS[lane], f1 = flagS[64 + lane];
        unsigned long long m0 = __ballot(f0 != 0);
        unsigned long long m1 = __ballot(f1 != 0);
        unsigned long long lt = (1ull << lane) - 1ull;
        int c0 = __popcll(m0);
        if (f0) listS[__popcll(m0 & lt)] = lane;
        if (f1) listS[c0 + __popcll(m1 & lt)] = 64 + lane;
        if (lane == 0) cntS = c0 + __popcll(m1);
    }
    __syncthreads();
    int cnt = cntS;
    int NT = (cnt + 15) >> 4;

    // ---- GEMM1 on active tiles: T1^T = Wf1^T(256x32) @ edge^T(32x|act|)
    const u16*  efb = ef + (size_t)row * 4096;
    const float* hpb = hn1p + (size_t)b * 32768;
    int mt0 = w * 2, mt1 = w * 2 + 1;
    bf16x8 aG0 = *(const bf16x8*)(wf1t + ((size_t)(l * 16 + mt0) * 64 + lane) * 8);
    bf16x8 aG1 = *(const bf16x8*)(wf1t + ((size_t)(l * 16 + mt1) * 64 + lane) * 8);
    for (int n = 0; n < NT; ++n) {
        int j = listS[n * 16 + (lane & 15)];
        int jo = (j >> 4) * 64 + (lane & 48) + (j & 15);
        bf16x8 be = *(const bf16x8*)(efb + (size_t)jo * 8);
        {
            f32x4 ci = *(const f32x4*)(hpb + ((size_t)(mt0 * 8) * 64 + jo) * 4);
            f32x4 acc = __builtin_amdgcn_mfma_f32_16x16x32_bf16(aG0, be, ci, 0, 0, 0);
            u32 lo = (u32)f2bf(fmaxf(acc[0], 0.f)) | ((u32)f2bf(fmaxf(acc[1], 0.f)) << 16);
            u32 hi = (u32)f2bf(fmaxf(acc[2], 0.f)) | ((u32)f2bf(fmaxf(acc[3], 0.f)) << 16);
            int g = ((mt0 & 1) << 1) | (lane >> 5), half = (lane >> 4) & 1;
            uint2 pk; pk.x = lo; pk.y = hi;
            *(uint2*)(t1S + ((size_t)((w * 8 + n) * 64) + g * 16 + (lane & 15)) * 8 + half * 4) = pk;
        }
        {
            f32x4 ci = *(const f32x4*)(hpb + ((size_t)(mt1 * 8) * 64 + jo) * 4);
            f32x4 acc = __builtin_amdgcn_mfma_f32_16x16x32_bf16(aG1, be, ci, 0, 0, 0);
            u32 lo = (u32)f2bf(fmaxf(acc[0], 0.f)) | ((u32)f2bf(fmaxf(acc[1], 0.f)) << 16);
            u32 hi = (u32)f2bf(fmaxf(acc[2], 0.f)) | ((u32)f2bf(fmaxf(acc[3], 0.f)) << 16);
            int g = ((mt1 & 1) << 1) | (lane >> 5), half = (lane >> 4) & 1;
            uint2 pk; pk.x = lo; pk.y = hi;
            *(uint2*)(t1S + ((size_t)((w * 8 + n) * 64) + g * 16 + (lane & 15)) * 8 + half * 4) = pk;
        }
    }
    __syncthreads();

    // ---- GEMM2 on active tiles: T2^T = W2^T(256x256) @ T1^T(256x|act|)
    bf16x8 a2[8][2];
#pragma unroll
    for (int kt = 0; kt < 8; ++kt) {
        a2[kt][0] = *(const bf16x8*)(w2t + ((size_t)((l * 8 + kt) * 16 + mt0) * 64 + lane) * 8);
        a2[kt][1] = *(const bf16x8*)(w2t + ((size_t)((l * 8 + kt) * 16 + mt1) * 64 + lane) * 8);
    }
    int hb0 = mt0 * 16 + (lane >> 4) * 4;
    int hb1 = mt1 * 16 + (lane >> 4) * 4;
    f32x4 bv0 = *(const f32x4*)(&b2S[hb0]);
    f32x4 bv1 = *(const f32x4*)(&b2S[hb1]);
    f32x4 ms0 = (f32x4){0.f, 0.f, 0.f, 0.f};
    f32x4 ms1 = (f32x4){0.f, 0.f, 0.f, 0.f};
    for (int n = 0; n < NT; ++n) {
        f32x4 acc0 = (f32x4){0.f, 0.f, 0.f, 0.f};
        f32x4 acc1 = (f32x4){0.f, 0.f, 0.f, 0.f};
#pragma unroll
        for (int kt = 0; kt < 8; ++kt) {
            bf16x8 bt = *(const bf16x8*)(t1S + ((size_t)(kt * 8 + n) * 64 + lane) * 8);
            acc0 = __builtin_amdgcn_mfma_f32_16x16x32_bf16(a2[kt][0], bt, acc0, 0, 0, 0);
            acc1 = __builtin_amdgcn_mfma_f32_16x16x32_bf16(a2[kt][1], bt, acc1, 0, 0, 0);
        }
        float aw = (n * 16 + (lane & 15)) < cnt ? 1.f : 0.f;
#pragma unroll
        for (int r = 0; r < 4; ++r) {
            ms0[r] += fmaxf(acc0[r] + bv0[r], 0.f) * aw;
            ms1[r] += fmaxf(acc1[r] + bv1[r], 0.f) * aw;
        }
    }
#pragma unroll
    for (int r = 0; r < 4; ++r) {
        ms0[r] += __shfl_xor(ms0[r], 1); ms1[r] += __shfl_xor(ms1[r], 1);
        ms0[r] += __shfl_xor(ms0[r], 2); ms1[r] += __shfl_xor(ms1[r], 2);
        ms0[r] += __shfl_xor(ms0[r], 4); ms1[r] += __shfl_xor(ms1[r], 4);
        ms0[r] += __shfl_xor(ms0[r], 8); ms1[r] += __shfl_xor(ms1[r], 8);
    }
    if ((lane & 15) == 0) {
        *(f32x4*)(&msgS[hb0]) = ms0;
        *(f32x4*)(&msgS[hb1]) = ms1;
    }
    __syncthreads();

    // ---- tail: residual + mask, then fused LN for next layer
    float v = 0.f;
    if (tid < 256) {
        float mv = (float)mask[row];
        v = (h[(size_t)row * 256 + tid] + msgS[tid]) * mv;
        h[(size_t)row * 256 + tid] = v;
    }
    float s = v, s2 = v * v;
#pragma unroll
    for (int off = 32; off; off >>= 1) {
        s  += __shfl_xor(s,  off);
        s2 += __shfl_xor(s2, off);
    }
    if (lane == 0) { rs[w] = s; rs2[w] = s2; }
    __syncthreads();
    if (doLN && tid < 256) {
        float S = 0.f, S2 = 0.f;
#pragma unroll
        for (int t = 0; t < 8; ++t) { S += rs[t]; S2 += rs2[t]; }
        float mu  = S * (1.f / 256.f);
        float var = S2 * (1.f / 256.f) - mu * mu;
        float rstd = rsqrtf(var + 1e-5f);
        hnbf[(size_t)row * 256 + tid] = f2bf((v - mu) * rstd * lngN[tid] + lnbN[tid]);
    }
}

// ---------------- readout ----------------

__global__ void k_ro1(const float* __restrict__ h, const float* __restrict__ pW,
                      const float* __restrict__ pb, const float* __restrict__ aW,
                      const float* __restrict__ ab, float* __restrict__ scores) {
    __shared__ float hr[8][256];
    __shared__ float red[4][8];
    int blk = blockIdx.x, b = blk >> 4, g = blk & 15;
    int tid = threadIdx.x;
    size_t base = (size_t)(b * 128 + g * 8) * 256;
#pragma unroll
    for (int t = 0; t < 8; ++t) hr[t][tid] = h[base + t * 256 + tid];
    __syncthreads();
    float facc[8];
    float pbv = pb[tid];
#pragma unroll
    for (int j = 0; j < 8; ++j) facc[j] = pbv;
    for (int k = 0; k < 256; ++k) {
        float wv = pW[(size_t)k * 256 + tid];
#pragma unroll
        for (int j = 0; j < 8; ++j) facc[j] += hr[j][k] * wv;
    }
    float awc = aW[tid];
    int w = tid >> 6, lane = tid & 63;
#pragma unroll
    for (int j = 0; j < 8; ++j) {
        float v = tanhf(facc[j]) * awc;
#pragma unroll
        for (int off = 32; off; off >>= 1) v += __shfl_xor(v, off);
        if (lane == 0) red[w][j] = v;
    }
    __syncthreads();
    if (tid < 8)
        scores[b * 128 + g * 8 + tid] = red[0][tid] + red[1][tid] + red[2][tid] + red[3][tid] + ab[0];
}

__global__ void k_ro2(const float* __restrict__ h, const float* __restrict__ scores,
                      const int* __restrict__ mask, const float* __restrict__ phW,
                      const float* __restrict__ phb, float* __restrict__ out) {
    __shared__ float aS[128];
    __shared__ float rm[4], rc[4], red[4];
    int b = blockIdx.x, tid = threadIdx.x, w = tid >> 6, lane = tid & 63;
    float mv = 0.f, sv = -__builtin_inff();
    if (tid < 128) {
        mv = (float)mask[b * 128 + tid];
        if (mv > 0.f) sv = scores[b * 128 + tid];
    }
    float mx = sv, cs = mv;
#pragma unroll
    for (int off = 32; off; off >>= 1) {
        mx = fmaxf(mx, __shfl_xor(mx, off));
        cs += __shfl_xor(cs, off);
    }
    if (lane == 0) { rm[w] = mx; rc[w] = cs; }
    __syncthreads();
    mx = fmaxf(fmaxf(rm[0], rm[1]), fmaxf(rm[2], rm[3]));
    float cnt = rc[0] + rc[1] + rc[2] + rc[3];
    float e = (tid < 128 && mv > 0.f) ? expf(sv - mx) : 0.f;
    float se = e;
#pragma unroll
    for (int off = 32; off; off >>= 1) se += __shfl_xor(se, off);
    if (lane == 0) red[w] = se;
    __syncthreads();
    float S = red[0] + red[1] + red[2] + red[3];
    if (tid < 128) {
        float a;
        if (S > 0.f) a = e / S;
        else         a = (mv > 0.f) ? 1.f / fmaxf(cnt, 1.f) : 0.f;
        aS[tid] = a;
    }
    __syncthreads();
    float g = 0.f;
    const float* hb = h + (size_t)b * 128 * 256;
    for (int n = 0; n < 128; ++n) g += aS[n] * hb[(size_t)n * 256 + tid];
    float p = g * phW[tid];
#pragma unroll
    for (int off = 32; off; off >>= 1) p += __shfl_xor(p, off);
    __syncthreads();
    if (lane == 0) red[w] = p;
    __syncthreads();
    if (tid == 0) out[b] = red[0] + red[1] + red[2] + red[3] + phb[0];
}

// ---------------- host ----------------
extern "C" void kernel_launch(void* const* d_in, const int* in_sizes, int n_in,
                              void* d_out, int out_size, void* d_ws, size_t ws_size,
                              hipStream_t stream) {
    const float* x    = (const float*)d_in[0];
    const int*   adj  = (const int*)  d_in[1];
    const float* ea   = (const float*)d_in[2];
    const int*   mask = (const int*)  d_in[3];
    const float* nW   = (const float*)d_in[4];
    const float* nb   = (const float*)d_in[5];
    const float* eW   = (const float*)d_in[6];
    const float* eb   = (const float*)d_in[7];
    const float* lng  = (const float*)d_in[8];
    const float* lnb  = (const float*)d_in[9];
    const float* W1   = (const float*)d_in[10];
    const float* b1   = (const float*)d_in[11];
    const float* W2   = (const float*)d_in[12];
    const float* b2   = (const float*)d_in[13];
    const float* ropW = (const float*)d_in[14];
    const float* ropb = (const float*)d_in[15];
    const float* roaW = (const float*)d_in[16];
    const float* roab = (const float*)d_in[17];
    const float* phW  = (const float*)d_in[18];
    const float* phb  = (const float*)d_in[19];
    float* out = (float*)d_out;

    char* p = (char*)d_ws;
    auto alloc = [&](size_t bytes) { char* r = p; p += (bytes + 255) & ~(size_t)255; return r; };
    float* h     = (float*)alloc((size_t)8 * 128 * 256 * 4);
    u16*   hnbf  = (u16*)  alloc((size_t)8 * 128 * 256 * 2);
    float* hn1p  = (float*)alloc((size_t)8 * 32768 * 4);
    u16*   ef    = (u16*)  alloc((size_t)8 * 128 * 4096 * 2);
    u16*   wf1t  = (u16*)  alloc((size_t)8 * 16 * 64 * 8 * 2);
    u16*   w1t   = (u16*)  alloc((size_t)8 * 8 * 16 * 64 * 8 * 2);
    u16*   w2t   = (u16*)  alloc((size_t)8 * 8 * 16 * 64 * 8 * 2);
    float* bias1 = (float*)alloc((size_t)8 * 256 * 4);
    float* scores= (float*)alloc((size_t)1024 * 4);

    k_h0ln    <<<1024, 256, 0, stream>>>(x, nW, nb, mask, lng, lnb, h, hnbf);
    k_edgefrag<<<2048, 256, 0, stream>>>(ea, ef);
    k_wt      <<<256,  256, 0, stream>>>(W1, W2, w1t, w2t);
    k_wf1b    <<<8,    256, 0, stream>>>(eW, eb, W1, b1, wf1t, bias1);

    for (int l = 0; l < 8; ++l) {
        k_hn1<<<128,  256, 0, stream>>>(w1t, hnbf, bias1, hn1p, l);
        int doLN = (l < 7) ? 1 : 0;
        int ln_next = (l < 7) ? (l + 1) : l;
        k_msg<<<1024, 512, 0, stream>>>(wf1t, ef, w2t, hn1p, b2, adj, mask, h,
                                        lng + ln_next * 256, lnb + ln_next * 256,
                                        hnbf, l, doLN);
    }

    k_ro1<<<128, 256, 0, stream>>>(h, ropW, ropb, roaW, roab, scores);
    k_ro2<<<8,   256, 0, stream>>>(h, scores, mask, phW, phb, out);
}